// Round 1
// baseline (64.665 us; speedup 1.0000x reference)
//
#include <hip/hip_runtime.h>
#include <math.h>

// Quantum autoencoder forward — barrier-free, LDS-free wave-resident simulator.
//
// Key ideas vs previous version:
//  - One wave (64 lanes) per batch sample; the 10-qubit state (1024 complex
//    amps) lives entirely in registers: 16 re + 16 im per lane.
//    Virtual index x' = (lane << 4) | reg  (lane = bits 4..9, reg = bits 0..3).
//  - The CNOT ring is a GF(2)-linear map L on basis indices. We never permute
//    data: we track t[x'] = s[P x'] and absorb each ring into P <- L*P.
//    An RX on physical bit p then acts on pairs {x', x' ^ v}, v = P^{-1} e_p —
//    a COMPILE-TIME constant mask per gate. RX is symmetric (equal
//    off-diagonals), so both pair halves use the same update formula:
//       new_r = fma(c, a_r,  s*partner_i)
//       new_i = fma(c, a_i, -s*partner_r)
//    (bit-identical arithmetic to the verified LDS kernel).
//  - Lane-crossing part of v -> __shfl_xor; reg part -> static reg re-index.
//  - Swap test: P(aux=1) = 0.5*(1 - sum_{phys idx & 7 == 0} |psi|^2). The
//    condition on x' is 3 constexpr parity rows of L^4. Wave shuffle reduce.

#define NQ     10
#define DEPTHL 4
#define NGATE  (NQ + DEPTHL * NQ)   // 50 RX gates

// wire w lives at bit position (NQ-1-w). Forward CNOT-ring cascade applied to
// an index: for w = 0..9: bit_{pos((w+1)%10)} ^= bit_{pos(w)}
constexpr int lfwd_step(int i) {
    for (int w = 0; w < NQ; ++w) {
        int cb = (i >> (NQ - 1 - w)) & 1;
        i ^= cb << (NQ - 1 - ((w + 1) % NQ));
    }
    return i;
}
// inverse: same xors, reverse order
constexpr int linv_step(int i) {
    for (int w = NQ - 1; w >= 0; --w) {
        int cb = (i >> (NQ - 1 - w)) & 1;
        i ^= cb << (NQ - 1 - ((w + 1) % NQ));
    }
    return i;
}

static_assert(lfwd_step(linv_step(0x155)) == 0x155, "linv must invert lfwd");
static_assert(linv_step(lfwd_step(0x2AB)) == 0x2AB, "lfwd must invert linv");

struct MaskTab { int m[NGATE]; int row[3]; };

constexpr MaskTab make_masks() {
    MaskTab M{};
    // embedding gates: frame P = I -> mask = e_pos(w)
    for (int w = 0; w < NQ; ++w) M.m[w] = 1 << (NQ - 1 - w);
    // entangler layer l gates run with P = L^l -> mask = Linv^l(e_pos(w))
    for (int l = 0; l < DEPTHL; ++l)
        for (int w = 0; w < NQ; ++w) {
            int v = 1 << (NQ - 1 - w);
            for (int k = 0; k < l; ++k) v = linv_step(v);
            M.m[NQ + NQ * l + w] = v;
        }
    // measurement parity rows: row p of L^4 (p = 0,1,2 = trash bit positions)
    for (int p = 0; p < 3; ++p) {
        int r = 0;
        for (int j = 0; j < NQ; ++j) {
            int y = 1 << j;
            for (int k = 0; k < DEPTHL; ++k) y = lfwd_step(y);
            r |= ((y >> p) & 1) << j;
        }
        M.row[p] = r;
    }
    return M;
}

constexpr MaskTab MK = make_masks();

constexpr bool masks_ok() {
    for (int g = 0; g < NGATE; ++g)
        if (MK.m[g] <= 0 || MK.m[g] > 1023) return false;
    return MK.row[0] && MK.row[1] && MK.row[2];
}
static_assert(masks_ok(), "gate masks must be nonzero 10-bit");

__global__ __launch_bounds__(64) void qae_kernel(
    const float* __restrict__ features,   // [B, 10]
    const float* __restrict__ weights,    // [4, 10] flat
    float* __restrict__ out)              // [B]
{
    const int b    = blockIdx.x;
    const int lane = threadIdx.x;         // 0..63, one full wave

    // ---- gate angle table: lane g holds (cos, sin) of gate g's half-angle ----
    float cg = 1.0f, sg = 0.0f;
    if (lane < NGATE) {
        float ang = (lane < NQ) ? features[b * NQ + lane] : weights[lane - NQ];
        float h = 0.5f * ang;
        cg = cosf(h);
        sg = sinf(h);
    }

    // ---- state |0...0> : amplitude 1 at x' = 0 (lane 0, reg 0) ----
    float tre[16], tim[16];
#pragma unroll
    for (int r = 0; r < 16; ++r) { tre[r] = 0.0f; tim[r] = 0.0f; }
    if (lane == 0) tre[0] = 1.0f;

    // ---- 50 RX gates; CNOT rings are absorbed into the constexpr masks ----
#pragma unroll
    for (int g = 0; g < NGATE; ++g) {
        const int v  = MK.m[g];           // compile-time after unroll
        const int lm = v >> 4;            // lane-crossing part
        const int rm = v & 15;            // in-thread reg part
        const float c = __shfl(cg, g, 64);  // v_readlane broadcast
        const float s = __shfl(sg, g, 64);

        float pre[16], pim[16];
        if (lm) {
#pragma unroll
            for (int r = 0; r < 16; ++r) {
                pre[r] = __shfl_xor(tre[r ^ rm], lm, 64);
                pim[r] = __shfl_xor(tim[r ^ rm], lm, 64);
            }
        } else {
#pragma unroll
            for (int r = 0; r < 16; ++r) {
                pre[r] = tre[r ^ rm];
                pim[r] = tim[r ^ rm];
            }
        }
#pragma unroll
        for (int r = 0; r < 16; ++r) {
            tre[r] = fmaf(c, tre[r],  s * pim[r]);
            tim[r] = fmaf(c, tim[r], -s * pre[r]);
        }
    }

    // ---- measurement: sum |t[x']|^2 over x' with (L^4 x') & 7 == 0 ----
    const int pl0 = __popc((MK.row[0] >> 4) & lane) & 1;
    const int pl1 = __popc((MK.row[1] >> 4) & lane) & 1;
    const int pl2 = __popc((MK.row[2] >> 4) & lane) & 1;

    float acc = 0.0f;
#pragma unroll
    for (int r = 0; r < 16; ++r) {
        const int pr0 = __popc(MK.row[0] & 15 & r) & 1;  // folds: r is literal
        const int pr1 = __popc(MK.row[1] & 15 & r) & 1;
        const int pr2 = __popc(MK.row[2] & 15 & r) & 1;
        const int bad = (pl0 ^ pr0) | (pl1 ^ pr1) | (pl2 ^ pr2);
        if (!bad) acc += tre[r] * tre[r] + tim[r] * tim[r];
    }

    // wave butterfly reduce (64 lanes)
#pragma unroll
    for (int off = 32; off; off >>= 1)
        acc += __shfl_xor(acc, off, 64);

    if (lane == 0) out[b] = 0.5f * (1.0f - acc);
}

extern "C" void kernel_launch(void* const* d_in, const int* in_sizes, int n_in,
                              void* d_out, int out_size, void* d_ws, size_t ws_size,
                              hipStream_t stream) {
    const float* features = (const float*)d_in[0];   // [B,10] float32
    const float* weights  = (const float*)d_in[1];   // [4,10] float32
    float*       out      = (float*)d_out;           // [B] float32

    int B = in_sizes[0] / NQ;                        // 256
    qae_kernel<<<B, 64, 0, stream>>>(features, weights, out);
}

// Round 2
// 58.356 us; speedup vs baseline: 1.1081x; 1.1081x over previous
//
#include <hip/hip_runtime.h>
#include <math.h>

// Quantum autoencoder forward — fully diagonalized closed form.
//
// Derivation chain (each step verified against the previously-passing kernel):
//  1. Trash wires 10..13 stay |0>; swap test reduces to
//       p = 0.5*(1 - sum_{phys & 7 == 0} |psi|^2)           [verified, session 1]
//  2. CNOT rings are GF(2)-linear maps L; absorb them into a frame P=L^l.
//     Every RX becomes exp(-i th/2 * X_v), X_v|x> = |x^v>, v = L^{-l} e_w
//     (compile-time masks MK.m).                            [verified, round 1]
//  3. ALL X_v commute and H^{ox10} diagonalizes them simultaneously:
//       U = H diag(e^{-i phi_y/2}) H,  phi_y = sum_g th_g * (-1)^{popc(v_g & y)}
//  4. From |0>, with S = {x : row_p . x = 0, p=0..2} (rows of L^4),
//     Poisson summation over the subgroup gives
//       T = sum_{x in S} |psi_x|^2 = 2^-16 * sum_y |Z_y|^2,
//     where Z_y = sum_{w in span{row0,row1,row2}} z_{y^w},  z_y = e^{-i phi_y/2}
//     (3 XOR-butterfly stages).  Sanity: th==0 -> Z=8, T=1, p=0. OK.
//
// Kernel: one wave per sample; y = (lane<<4)|r. ~50 uniform scalar loads,
// ~1000 VALU, 16 sincos, 3 shuffle stages, 1 wave reduce. No LDS, no barriers.

#define NQ     10
#define DEPTHL 4
#define NSLOT  (NQ + DEPTHL * NQ)   // 50 raw angle slots

// wire w lives at bit position (NQ-1-w). CNOT-ring cascade on an index:
constexpr int lfwd_step(int i) {
    for (int w = 0; w < NQ; ++w) {
        int cb = (i >> (NQ - 1 - w)) & 1;
        i ^= cb << (NQ - 1 - ((w + 1) % NQ));
    }
    return i;
}
constexpr int linv_step(int i) {
    for (int w = NQ - 1; w >= 0; --w) {
        int cb = (i >> (NQ - 1 - w)) & 1;
        i ^= cb << (NQ - 1 - ((w + 1) % NQ));
    }
    return i;
}
static_assert(lfwd_step(linv_step(0x155)) == 0x155, "linv must invert lfwd");
static_assert(linv_step(lfwd_step(0x2AB)) == 0x2AB, "lfwd must invert linv");

struct MaskTab { int m[NSLOT]; int row[3]; };

constexpr MaskTab make_masks() {
    MaskTab M{};
    // embedding slot w (angle features[b,w]): frame I -> mask e_pos(w)
    for (int w = 0; w < NQ; ++w) M.m[w] = 1 << (NQ - 1 - w);
    // entangler layer l wire w (angle weights[10l+w]): mask = Linv^l(e_pos(w))
    for (int l = 0; l < DEPTHL; ++l)
        for (int w = 0; w < NQ; ++w) {
            int v = 1 << (NQ - 1 - w);
            for (int k = 0; k < l; ++k) v = linv_step(v);
            M.m[NQ + NQ * l + w] = v;
        }
    // measurement parity rows: row p of L^4 (trash bit positions p = 0,1,2)
    for (int p = 0; p < 3; ++p) {
        int r = 0;
        for (int j = 0; j < NQ; ++j) {
            int y = 1 << j;
            for (int k = 0; k < DEPTHL; ++k) y = lfwd_step(y);
            r |= ((y >> p) & 1) << j;
        }
        M.row[p] = r;
    }
    return M;
}
constexpr MaskTab MK = make_masks();

constexpr bool masks_ok() {
    for (int g = 0; g < NSLOT; ++g)
        if (MK.m[g] <= 0 || MK.m[g] > 1023) return false;
    return MK.row[0] && MK.row[1] && MK.row[2];
}
static_assert(masks_ok(), "gate masks must be nonzero 10-bit");

constexpr bool rows_indep() {   // all 7 nonzero GF(2) combos nonzero <=> rank 3
    int a = MK.row[0], b = MK.row[1], c = MK.row[2];
    return a && b && c && (a ^ b) && (a ^ c) && (b ^ c) && (a ^ b ^ c);
}
static_assert(rows_indep(), "measurement rows must be linearly independent");

__global__ __launch_bounds__(64) void qae_kernel(
    const float* __restrict__ features,   // [B, 10]
    const float* __restrict__ weights,    // [4, 10] flat
    float* __restrict__ out)              // [B]
{
    const int b    = blockIdx.x;
    const int lane = threadIdx.x;         // 0..63; y = (lane<<4) | r

    // ---- phi_y = sum_t theta_t * (-1)^{popc(M_t & y)} -------------------
    float phi[16];
#pragma unroll
    for (int r = 0; r < 16; ++r) phi[r] = 0.0f;

#pragma unroll
    for (int t = 0; t < NSLOT; ++t) {
        const int v = MK.m[t];                       // compile-time constant
        // uniform (scalar) load: same address for all lanes of the block
        const float th = (t < NQ) ? features[b * NQ + t] : weights[t - NQ];
        // lane-borne sign: parity of popc((v>>4) & lane)
        const int par = __popc((v >> 4) & lane) & 1;
        const float tv = par ? -th : th;
        // reg-borne sign is compile-time per (t, r): folds to add or sub
#pragma unroll
        for (int r = 0; r < 16; ++r) {
            if (__popc(v & 15 & r) & 1) phi[r] -= tv;
            else                        phi[r] += tv;
        }
    }

    // ---- z_y = e^{-i phi/2}  (store conj; |Z|^2 is conjugation-invariant) --
    float zr[16], zi[16];
#pragma unroll
    for (int r = 0; r < 16; ++r) {
        float sv, cv;
        sincosf(0.5f * phi[r], &sv, &cv);  // accurate variant for safety
        zr[r] = cv;
        zi[r] = sv;
    }

    // ---- 3 XOR-butterfly stages: Z_y = sum_{w in span{rows}} z_{y^w} ------
#pragma unroll
    for (int p = 0; p < 3; ++p) {
        const int w  = MK.row[p];
        const int wl = w >> 4;             // lane-crossing part
        const int wr = w & 15;             // in-thread reg part
        float tr[16], ti[16];
        if (wl) {
#pragma unroll
            for (int r = 0; r < 16; ++r) {
                tr[r] = __shfl_xor(zr[r ^ wr], wl, 64);
                ti[r] = __shfl_xor(zi[r ^ wr], wl, 64);
            }
        } else {
#pragma unroll
            for (int r = 0; r < 16; ++r) {
                tr[r] = zr[r ^ wr];
                ti[r] = zi[r ^ wr];
            }
        }
#pragma unroll
        for (int r = 0; r < 16; ++r) { zr[r] += tr[r]; zi[r] += ti[r]; }
    }

    // ---- T = 2^-16 * sum_y |Z_y|^2 ;  p = 0.5*(1 - T) ---------------------
    float acc = 0.0f;
#pragma unroll
    for (int r = 0; r < 16; ++r)
        acc = fmaf(zr[r], zr[r], fmaf(zi[r], zi[r], acc));

#pragma unroll
    for (int off = 32; off; off >>= 1)
        acc += __shfl_xor(acc, off, 64);

    if (lane == 0)
        out[b] = 0.5f * (1.0f - acc * (1.0f / 65536.0f));
}

extern "C" void kernel_launch(void* const* d_in, const int* in_sizes, int n_in,
                              void* d_out, int out_size, void* d_ws, size_t ws_size,
                              hipStream_t stream) {
    const float* features = (const float*)d_in[0];   // [B,10] float32
    const float* weights  = (const float*)d_in[1];   // [4,10] float32
    float*       out      = (float*)d_out;           // [B] float32

    int B = in_sizes[0] / NQ;                        // 256
    qae_kernel<<<B, 64, 0, stream>>>(features, weights, out);
}